// Round 3
// baseline (320.783 us; speedup 1.0000x reference)
//
#include <hip/hip_runtime.h>
#include <hip/hip_fp16.h>
#include <math.h>

// QFF1: per point n, per freq f: enc[m=s*3+d] = {sin,cos}(p_d * freq_f)
// pos=(enc+1)*39.5; lerp into table qv[f*6+m][cr][q];
// out[n][f*8 + s*4 + c] = sum_r prod_d lerp(m=s*3+d, cr=c*8+r)
//
// One block = 512 points x ALL 6 freqs. Per-freq fp16 tables double-buffered
// in LDS ([m][q][40-half rows] -> 80-B row stride; bank-group of chunk jc at
// row q = (5q+jc)&7, 5 coprime 8 => random rows spread over all groups).
// acc[48] in registers; single full-row coalesced write at the end kills the
// partial-line write amplification seen in R2 (196 MB -> 25 MB).

constexpr int N_POINTS = 131072;
constexpr int NFREQ    = 6;
constexpr int QN       = 80;
constexpr int CRN      = 32;   // NUM_FEATS(4) * NUM_CORRS(8)
constexpr int M_PER_F  = 6;    // {sin,cos} x 3 dims
constexpr int THREADS  = 512;
constexpr int ROW      = 40;                      // halves per q-row (80 B)
constexpr int MSTRIDE  = QN * ROW;                // 3200 halves per table
constexpr int FSTRIDE  = M_PER_F * MSTRIDE;       // 19200 halves per freq buf
constexpr int STAGE_H2 = M_PER_F * QN * (CRN/2);  // 7680 half2 per freq
constexpr int SPT      = STAGE_H2 / THREADS;      // 15 half2 per thread

__global__ __launch_bounds__(THREADS, 2)
void qff1_kernel(const float* __restrict__ points,
                 const float* __restrict__ qff,
                 const float* __restrict__ freqs,
                 float* __restrict__ out)
{
    __shared__ __align__(16) __half lds[2 * FSTRIDE];   // 76800 B

    const int tid = threadIdx.x;
    const int n = blockIdx.x * THREADS + tid;

    const float px = points[n * 3 + 0];
    const float py = points[n * 3 + 1];
    const float pz = points[n * 3 + 2];

    // loop-invariant staging coordinates
    int srcoff[SPT], dstoff[SPT];
#pragma unroll
    for (int k = 0; k < SPT; ++k) {
        int idx = tid + k * THREADS;
        int m   = idx / (QN * (CRN / 2));
        int rem = idx - m * (QN * (CRN / 2));
        int q   = rem >> 4;
        int cr2 = rem & 15;
        srcoff[k] = m * (CRN * QN) + (2 * cr2) * QN + q;   // +QN for odd cr
        dstoff[k] = m * (MSTRIDE / 2) + q * (ROW / 2) + cr2;
    }

    float sv0[SPT], sv1[SPT];

    // prologue: stage f=0 into buffer 0
#pragma unroll
    for (int k = 0; k < SPT; ++k) {
        sv0[k] = qff[srcoff[k]];
        sv1[k] = qff[srcoff[k] + QN];
    }
    {
        __half2* dst = reinterpret_cast<__half2*>(lds);
#pragma unroll
        for (int k = 0; k < SPT; ++k)
            dst[dstoff[k]] = __floats2half2_rn(sv0[k], sv1[k]);
    }
    __syncthreads();

    float acc[48];

#pragma unroll
    for (int f = 0; f < NFREQ; ++f) {
        // T14 issue-early: next freq's global loads go in flight now,
        // land in LDS after this freq's compute.
        if (f + 1 < NFREQ) {
            const float* tab = qff + (size_t)(f + 1) * (M_PER_F * CRN * QN);
#pragma unroll
            for (int k = 0; k < SPT; ++k) {
                sv0[k] = tab[srcoff[k]];
                sv1[k] = tab[srcoff[k] + QN];
            }
        }

        const __half* L = lds + (f & 1) * FSTRIDE;
        const float freq = freqs[f];

        float enc[6];
        {
            float s, c;
            __sincosf(px * freq, &s, &c); enc[0] = s; enc[3] = c;
            __sincosf(py * freq, &s, &c); enc[1] = s; enc[4] = c;
            __sincosf(pz * freq, &s, &c); enc[2] = s; enc[5] = c;
        }

        int b0[6], b1[6];
        __half2 w2[6];
#pragma unroll
        for (int m = 0; m < 6; ++m) {
            float pos = (enc[m] + 1.0f) * (0.5f * (float)(QN - 1));
            float fi  = floorf(pos);
            int i0    = (int)fi;
            i0 = i0 < 0 ? 0 : (i0 > QN - 1 ? QN - 1 : i0);
            int i1 = i0 + 1; if (i1 > QN - 1) i1 = QN - 1;
            w2[m] = __float2half2_rn(pos - (float)i0);
            b0[m] = m * MSTRIDE + i0 * ROW;
            b1[m] = m * MSTRIDE + i1 * ROW;
        }

#pragma unroll
        for (int s = 0; s < 2; ++s) {
#pragma unroll
            for (int jc = 0; jc < 4; ++jc) {   // 16B chunk = feature c=jc, ranks 0..7
                __half2 Lv[3][4];
#pragma unroll
                for (int d = 0; d < 3; ++d) {
                    int m = s * 3 + d;
                    union { float4 v; __half2 h[4]; } A, B;
                    A.v = *(const float4*)&L[b0[m] + jc * 8];
                    B.v = *(const float4*)&L[b1[m] + jc * 8];
#pragma unroll
                    for (int kk = 0; kk < 4; ++kk)
                        Lv[d][kk] = __hfma2(w2[m], __hsub2(B.h[kk], A.h[kk]), A.h[kk]);
                }
                float a = 0.0f;
#pragma unroll
                for (int kk = 0; kk < 4; ++kk) {
                    float2 f0 = __half22float2(Lv[0][kk]);
                    float2 f1 = __half22float2(Lv[1][kk]);
                    float2 f2 = __half22float2(Lv[2][kk]);
                    a += f0.x * f1.x * f2.x + f0.y * f1.y * f2.y;
                }
                acc[f * 8 + s * 4 + jc] = a;
            }
        }

        // write-late: convert + LDS-write the prefetched next-freq tables
        if (f + 1 < NFREQ) {
            __half2* dst = reinterpret_cast<__half2*>(lds + ((f + 1) & 1) * FSTRIDE);
#pragma unroll
            for (int k = 0; k < SPT; ++k)
                dst[dstoff[k]] = __floats2half2_rn(sv0[k], sv1[k]);
        }
        __syncthreads();
    }

    // full 192-B rows per thread; wave covers a dense 96-KB span -> no RMW
    float4* o = (float4*)(out + (size_t)n * 48);
#pragma unroll
    for (int i = 0; i < 12; ++i)
        o[i] = make_float4(acc[4*i], acc[4*i+1], acc[4*i+2], acc[4*i+3]);
}

extern "C" void kernel_launch(void* const* d_in, const int* in_sizes, int n_in,
                              void* d_out, int out_size, void* d_ws, size_t ws_size,
                              hipStream_t stream) {
    const float* points = (const float*)d_in[0];   // (131072, 3)
    const float* qff    = (const float*)d_in[1];   // (36, 32, 80, 1)
    const float* freqs  = (const float*)d_in[2];   // (6,)
    float* out = (float*)d_out;                    // (131072, 48)

    dim3 grid(N_POINTS / THREADS);
    dim3 block(THREADS);
    qff1_kernel<<<grid, block, 0, stream>>>(points, qff, freqs, out);
}

// Round 4
// 93.115 us; speedup vs baseline: 3.4450x; 3.4450x over previous
//
#include <hip/hip_runtime.h>
#include <hip/hip_fp16.h>
#include <math.h>

// QFF1: per point n, per freq f: enc[m=s*3+d] = {sin,cos}(p_d * freq_f)
// pos=(enc+1)*39.5; lerp into table qv[f*6+m][cr][q];
// out[n][f*8 + s*4 + c] = sum_r prod_d lerp(m=s*3+d, cr=c*8+r)
//
// Structure: one (point-chunk, freq) pair per block (register-lean, VGPR=32),
// fp16 tables in LDS, [m][q][40-half rows] (80-B row stride; bank-group of
// 16B chunk jc at row q = (5q+jc)&7, 5 coprime 8 => random rows spread over
// all 8 groups).
//
// Write-amplification fix (R2's failure): XCD-grouped assignment. HW assigns
// XCD = blockIdx % 8; we map x=bid&7, j=bid>>3, f=j%6, chunk=x+8*(j/6) so all
// 6 freq-blocks of one 512-point chunk run consecutively on the SAME XCD's
// L2. Their disjoint 32-B row fragments fully cover the chunk's 98-KB output
// region while L2-resident -> full-line writebacks, no RMW.

constexpr int N_POINTS = 131072;
constexpr int NFREQ    = 6;
constexpr int QN       = 80;
constexpr int CRN      = 32;   // NUM_FEATS(4) * NUM_CORRS(8)
constexpr int M_PER_F  = 6;    // {sin,cos} x 3 dims
constexpr int THREADS  = 512;
constexpr int ROW      = 40;           // halves per row (80 B)
constexpr int MSTRIDE  = QN * ROW;     // 3200 halves per table
constexpr int NCHUNK   = N_POINTS / THREADS;   // 256

__global__ __launch_bounds__(THREADS, 8)
void qff1_kernel(const float* __restrict__ points,
                 const float* __restrict__ qff,
                 const float* __restrict__ freqs,
                 float* __restrict__ out)
{
    __shared__ __align__(16) __half lds[M_PER_F * MSTRIDE];   // 38400 B

    const int tid = threadIdx.x;
    const int bid = blockIdx.x;
    const int x   = bid & 7;          // XCD (hw: round-robin by blockIdx)
    const int j   = bid >> 3;         // issue order within this XCD
    const int f   = j % NFREQ;
    const int c   = x + 8 * (j / NFREQ);   // point chunk, c % 8 == XCD
    const int n   = c * THREADS + tid;

    const float freq = freqs[f];

    // ---- stage fp16 tables, dst-linear (conflict-free b32 LDS writes)
    const float* tab = qff + (size_t)f * (M_PER_F * CRN * QN);
    __half2* lds2 = reinterpret_cast<__half2*>(lds);
    for (int idx = tid; idx < M_PER_F * QN * (CRN / 2); idx += THREADS) {
        int m   = idx / (QN * CRN / 2);
        int rem = idx - m * (QN * CRN / 2);
        int q   = rem >> 4;
        int cr2 = rem & 15;
        float v0 = tab[m * (CRN * QN) + (2 * cr2    ) * QN + q];
        float v1 = tab[m * (CRN * QN) + (2 * cr2 + 1) * QN + q];
        lds2[m * (MSTRIDE / 2) + q * (ROW / 2) + cr2] = __floats2half2_rn(v0, v1);
    }
    __syncthreads();

    const float px = points[n * 3 + 0];
    const float py = points[n * 3 + 1];
    const float pz = points[n * 3 + 2];

    float enc[6];
    {
        float s, cc;
        __sincosf(px * freq, &s, &cc); enc[0] = s; enc[3] = cc;
        __sincosf(py * freq, &s, &cc); enc[1] = s; enc[4] = cc;
        __sincosf(pz * freq, &s, &cc); enc[2] = s; enc[5] = cc;
    }

    int b0[6], b1[6];
    __half2 w2[6];
#pragma unroll
    for (int m = 0; m < 6; ++m) {
        float pos = (enc[m] + 1.0f) * (0.5f * (float)(QN - 1));
        float fi  = floorf(pos);
        int i0    = (int)fi;
        i0 = i0 < 0 ? 0 : (i0 > QN - 1 ? QN - 1 : i0);
        int i1 = i0 + 1; if (i1 > QN - 1) i1 = QN - 1;
        w2[m] = __float2half2_rn(pos - (float)i0);
        b0[m] = m * MSTRIDE + i0 * ROW;
        b1[m] = m * MSTRIDE + i1 * ROW;
    }

    float acc[8];
#pragma unroll
    for (int s = 0; s < 2; ++s) {
#pragma unroll
        for (int jc = 0; jc < 4; ++jc) {   // 16B chunk = feature c=jc, ranks 0..7
            __half2 Lv[3][4];
#pragma unroll
            for (int d = 0; d < 3; ++d) {
                int m = s * 3 + d;
                union { float4 v; __half2 h[4]; } A, B;
                A.v = *(const float4*)&lds[b0[m] + jc * 8];
                B.v = *(const float4*)&lds[b1[m] + jc * 8];
#pragma unroll
                for (int kk = 0; kk < 4; ++kk)
                    Lv[d][kk] = __hfma2(w2[m], __hsub2(B.h[kk], A.h[kk]), A.h[kk]);
            }
            float a = 0.0f;
#pragma unroll
            for (int kk = 0; kk < 4; ++kk) {
                float2 f0 = __half22float2(Lv[0][kk]);
                float2 f1 = __half22float2(Lv[1][kk]);
                float2 f2 = __half22float2(Lv[2][kk]);
                a += f0.x * f1.x * f2.x + f0.y * f1.y * f2.y;
            }
            acc[s * 4 + jc] = a;
        }
    }

    float4* o = (float4*)(out + (size_t)n * 48 + f * 8);
    o[0] = make_float4(acc[0], acc[1], acc[2], acc[3]);
    o[1] = make_float4(acc[4], acc[5], acc[6], acc[7]);
}

extern "C" void kernel_launch(void* const* d_in, const int* in_sizes, int n_in,
                              void* d_out, int out_size, void* d_ws, size_t ws_size,
                              hipStream_t stream) {
    const float* points = (const float*)d_in[0];   // (131072, 3)
    const float* qff    = (const float*)d_in[1];   // (36, 32, 80, 1)
    const float* freqs  = (const float*)d_in[2];   // (6,)
    float* out = (float*)d_out;                    // (131072, 48)

    dim3 grid(NCHUNK * NFREQ);   // 1536, 1-D: bid&7 -> XCD group
    dim3 block(THREADS);
    qff1_kernel<<<grid, block, 0, stream>>>(points, qff, freqs, out);
}